// Round 1
// baseline (599.567 us; speedup 1.0000x reference)
//
#include <hip/hip_runtime.h>

#define NNODE 8192
#define NEDGE 4096
#define NCH   256
#define EPSV  1e-6f

typedef float  f32x4  __attribute__((ext_vector_type(4)));
typedef short  bf16x8 __attribute__((ext_vector_type(8)));
typedef unsigned short u16;
typedef unsigned int   u32;

static __device__ __forceinline__ u16 f2bf(float f) {
  union { float f; u32 u; } c; c.f = f;
  return (u16)((c.u + 0x7FFFu + ((c.u >> 16) & 1u)) >> 16);  // RNE
}

// ---------------------------------------------------------------------------
// prep_h: one pass over H (f32, [NNODE][NEDGE]):
//   - d_v[n] += row sums, d_e[e] += col sums (LDS partials -> global atomics)
//   - HbT[e][n] = bf16(H[n][e])   (LDS-tiled 64x64 transpose)
// grid (NNODE/64, NEDGE/64), 256 threads
// ---------------------------------------------------------------------------
__global__ __launch_bounds__(256) void prep_h(const float* __restrict__ H,
                                              u16* __restrict__ HbT,
                                              float* __restrict__ d_v,
                                              float* __restrict__ d_e) {
  __shared__ u16  Tb[64][65];
  __shared__ float rs[64], cs[64];
  const int tid = threadIdx.x;
  const int r0 = blockIdx.x * 64;   // node block
  const int c0 = blockIdx.y * 64;   // edge block
  if (tid < 64) { rs[tid] = 0.f; cs[tid] = 0.f; }
  __syncthreads();

  const int rowb = tid >> 4;        // 0..15
  const int c4   = tid & 15;        // 0..15 (float4 chunk)
  float colacc[4] = {0.f, 0.f, 0.f, 0.f};
  #pragma unroll
  for (int it = 0; it < 4; ++it) {
    const int row = rowb + it * 16;
    const float4 v = *(const float4*)&H[(size_t)(r0 + row) * NEDGE + c0 + c4 * 4];
    atomicAdd(&rs[row], v.x + v.y + v.z + v.w);
    colacc[0] += v.x; colacc[1] += v.y; colacc[2] += v.z; colacc[3] += v.w;
    Tb[row][c4 * 4 + 0] = f2bf(v.x);
    Tb[row][c4 * 4 + 1] = f2bf(v.y);
    Tb[row][c4 * 4 + 2] = f2bf(v.z);
    Tb[row][c4 * 4 + 3] = f2bf(v.w);
  }
  #pragma unroll
  for (int j = 0; j < 4; ++j) atomicAdd(&cs[c4 * 4 + j], colacc[j]);
  __syncthreads();

  // transposed write: HbT[c0+c][r0 + ch*8 .. +7], 512 chunks of 8 bf16
  for (int idx = tid; idx < 512; idx += 256) {
    const int c = idx >> 3, ch = idx & 7;
    u16 pk[8];
    #pragma unroll
    for (int e = 0; e < 8; ++e) pk[e] = Tb[ch * 8 + e][c];
    u32 w0 = (u32)pk[0] | ((u32)pk[1] << 16);
    u32 w1 = (u32)pk[2] | ((u32)pk[3] << 16);
    u32 w2 = (u32)pk[4] | ((u32)pk[5] << 16);
    u32 w3 = (u32)pk[6] | ((u32)pk[7] << 16);
    uint4 v; v.x = w0; v.y = w1; v.z = w2; v.w = w3;
    *(uint4*)&HbT[(size_t)(c0 + c) * NNODE + r0 + ch * 8] = v;
  }
  if (tid < 64)       atomicAdd(&d_e[c0 + tid], cs[tid]);
  else if (tid < 128) atomicAdd(&d_v[r0 + tid - 64], rs[tid - 64]);
}

// ---------------------------------------------------------------------------
// prep_x: xsT[c][n] = bf16( x[n][c] * rsqrt(d_v[n]+eps) ), [NCH][NNODE]
// grid (NNODE/32, NCH/64), 256 threads
// ---------------------------------------------------------------------------
__global__ __launch_bounds__(256) void prep_x(const float* __restrict__ x,
                                              const float* __restrict__ d_v,
                                              u16* __restrict__ xsT) {
  const int tid = threadIdx.x;
  const int c  = blockIdx.y * 64 + (tid & 63);
  const int n0 = blockIdx.x * 32 + (tid >> 6) * 8;
  u16 pk[8];
  #pragma unroll
  for (int i = 0; i < 8; ++i) {
    const int n = n0 + i;
    const float s = rsqrtf(d_v[n] + EPSV);
    pk[i] = f2bf(x[(size_t)n * NCH + c] * s);
  }
  u32 w0 = (u32)pk[0] | ((u32)pk[1] << 16);
  u32 w1 = (u32)pk[2] | ((u32)pk[3] << 16);
  u32 w2 = (u32)pk[4] | ((u32)pk[5] << 16);
  u32 w3 = (u32)pk[6] | ((u32)pk[7] << 16);
  uint4 v; v.x = w0; v.y = w1; v.z = w2; v.w = w3;
  *(uint4*)&xsT[(size_t)c * NNODE + n0] = v;
}

// prep_w: Wb = bf16(W), 65536 elems; grid 32, 256 threads (8 elems/thread)
__global__ __launch_bounds__(256) void prep_w(const float* __restrict__ W,
                                              u16* __restrict__ Wb) {
  const int i = (blockIdx.x * 256 + threadIdx.x) * 8;
  const float4 a = *(const float4*)&W[i];
  const float4 b = *(const float4*)&W[i + 4];
  u32 w0 = (u32)f2bf(a.x) | ((u32)f2bf(a.y) << 16);
  u32 w1 = (u32)f2bf(a.z) | ((u32)f2bf(a.w) << 16);
  u32 w2 = (u32)f2bf(b.x) | ((u32)f2bf(b.y) << 16);
  u32 w3 = (u32)f2bf(b.z) | ((u32)f2bf(b.w) << 16);
  uint4 v; v.x = w0; v.y = w1; v.z = w2; v.w = w3;
  *(uint4*)&Wb[i] = v;
}

// ---------------------------------------------------------------------------
// NT GEMM: C[m][n] = sum_k A[m][k] * Bt[n][k]   (bf16 MFMA 16x16x32, f32 acc)
// 256 threads = 4 waves (2x2), BK=64, XOR-swizzled LDS (16B chunk granule).
// EPI=1: A bf16; C -> tT[c][e] bf16, scale 1/(d_e[e]+eps)        (GEMM1)
// EPI=2: A f32 (converted in staging); C -> omid[node][c] bf16,
//        scale rsqrt(d_v[node]+eps)                               (GEMM2)
// EPI=3: A bf16; C -> f32 out[node][o] + bias[o]                  (GEMM3)
// ---------------------------------------------------------------------------
template <int BM, int BN, int EPI>
__global__ __launch_bounds__(256) void gemm_nt(const void* __restrict__ Aptr,
                                               const u16* __restrict__ Bt,
                                               int M, int N, int K,
                                               const float* __restrict__ scaleV,
                                               void* __restrict__ Cout) {
  constexpr int BK = 64;
  constexpr int FM = BM / 32, FN = BN / 32;
  __shared__ u16 lds_a[BM * BK];
  __shared__ u16 lds_b[BN * BK];

  const int tid  = threadIdx.x;
  const int lane = tid & 63;
  const int w    = tid >> 6;
  const int wm   = w >> 1, wn = w & 1;
  const int m0   = blockIdx.x * BM;
  const int n0   = blockIdx.y * BN;

  f32x4 acc[FM][FN];
  #pragma unroll
  for (int fm = 0; fm < FM; ++fm)
    #pragma unroll
    for (int fn = 0; fn < FN; ++fn)
      acc[fm][fn] = (f32x4){0.f, 0.f, 0.f, 0.f};

  for (int kt = 0; kt < K; kt += BK) {
    __syncthreads();
    // ---- stage A tile [BM][BK] ----
    if constexpr (EPI == 2) {
      const float* A = (const float*)Aptr;
      for (int idx = tid; idx < BM * 8; idx += 256) {
        const int row = idx >> 3, ch = idx & 7;
        const size_t g = (size_t)(m0 + row) * K + kt + ch * 8;
        const float4 v0 = *(const float4*)&A[g];
        const float4 v1 = *(const float4*)&A[g + 4];
        u32 w0 = (u32)f2bf(v0.x) | ((u32)f2bf(v0.y) << 16);
        u32 w1 = (u32)f2bf(v0.z) | ((u32)f2bf(v0.w) << 16);
        u32 w2 = (u32)f2bf(v1.x) | ((u32)f2bf(v1.y) << 16);
        u32 w3 = (u32)f2bf(v1.z) | ((u32)f2bf(v1.w) << 16);
        uint4 pv; pv.x = w0; pv.y = w1; pv.z = w2; pv.w = w3;
        *(uint4*)&lds_a[row * BK + ((ch ^ (row & 7)) * 8)] = pv;
      }
    } else {
      const u16* A = (const u16*)Aptr;
      for (int idx = tid; idx < BM * 8; idx += 256) {
        const int row = idx >> 3, ch = idx & 7;
        *(uint4*)&lds_a[row * BK + ((ch ^ (row & 7)) * 8)] =
            *(const uint4*)&A[(size_t)(m0 + row) * K + kt + ch * 8];
      }
    }
    // ---- stage B tile [BN][BK] from Bt ([N][K] layout) ----
    for (int idx = tid; idx < BN * 8; idx += 256) {
      const int row = idx >> 3, ch = idx & 7;
      *(uint4*)&lds_b[row * BK + ((ch ^ (row & 7)) * 8)] =
          *(const uint4*)&Bt[(size_t)(n0 + row) * K + kt + ch * 8];
    }
    __syncthreads();

    #pragma unroll
    for (int kk = 0; kk < 2; ++kk) {
      bf16x8 af[FM], bfv[FN];
      #pragma unroll
      for (int fm = 0; fm < FM; ++fm) {
        const int row = wm * (BM / 2) + fm * 16 + (lane & 15);
        const int ch  = kk * 4 + (lane >> 4);
        af[fm] = *(const bf16x8*)&lds_a[row * BK + ((ch ^ (row & 7)) * 8)];
      }
      #pragma unroll
      for (int fn = 0; fn < FN; ++fn) {
        const int row = wn * (BN / 2) + fn * 16 + (lane & 15);
        const int ch  = kk * 4 + (lane >> 4);
        bfv[fn] = *(const bf16x8*)&lds_b[row * BK + ((ch ^ (row & 7)) * 8)];
      }
      #pragma unroll
      for (int fm = 0; fm < FM; ++fm)
        #pragma unroll
        for (int fn = 0; fn < FN; ++fn)
          acc[fm][fn] = __builtin_amdgcn_mfma_f32_16x16x32_bf16(
              af[fm], bfv[fn], acc[fm][fn], 0, 0, 0);
    }
  }

  // ---- epilogue ----
  // D frag layout (verified): row = m + (lane>>4)*4 + r, col = n + (lane&15)
  if constexpr (EPI == 1) {
    u16* tT = (u16*)Cout;
    #pragma unroll
    for (int fm = 0; fm < FM; ++fm) {
      const int e_base = m0 + wm * (BM / 2) + fm * 16 + ((lane >> 4) << 2);
      float inv[4];
      #pragma unroll
      for (int r = 0; r < 4; ++r) inv[r] = 1.0f / (scaleV[e_base + r] + EPSV);
      #pragma unroll
      for (int fn = 0; fn < FN; ++fn) {
        const int c = n0 + wn * (BN / 2) + fn * 16 + (lane & 15);
        u16 pk[4];
        #pragma unroll
        for (int r = 0; r < 4; ++r) pk[r] = f2bf(acc[fm][fn][r] * inv[r]);
        uint2 v;
        v.x = (u32)pk[0] | ((u32)pk[1] << 16);
        v.y = (u32)pk[2] | ((u32)pk[3] << 16);
        *(uint2*)&tT[(size_t)c * M + e_base] = v;   // transposed store, 8B
      }
    }
  } else if constexpr (EPI == 2) {
    u16* om = (u16*)Cout;
    #pragma unroll
    for (int fm = 0; fm < FM; ++fm) {
      const int nb = m0 + wm * (BM / 2) + fm * 16 + ((lane >> 4) << 2);
      float s[4];
      #pragma unroll
      for (int r = 0; r < 4; ++r) s[r] = rsqrtf(scaleV[nb + r] + EPSV);
      #pragma unroll
      for (int fn = 0; fn < FN; ++fn) {
        const int c = n0 + wn * (BN / 2) + fn * 16 + (lane & 15);
        #pragma unroll
        for (int r = 0; r < 4; ++r)
          om[(size_t)(nb + r) * NCH + c] = f2bf(acc[fm][fn][r] * s[r]);
      }
    }
  } else {
    float* o = (float*)Cout;
    #pragma unroll
    for (int fm = 0; fm < FM; ++fm) {
      const int nb = m0 + wm * (BM / 2) + fm * 16 + ((lane >> 4) << 2);
      #pragma unroll
      for (int fn = 0; fn < FN; ++fn) {
        const int ccol = n0 + wn * (BN / 2) + fn * 16 + (lane & 15);
        const float bias = scaleV[ccol];
        #pragma unroll
        for (int r = 0; r < 4; ++r)
          o[(size_t)(nb + r) * NCH + ccol] = acc[fm][fn][r] + bias;
      }
    }
  }
}

// ---------------------------------------------------------------------------
extern "C" void kernel_launch(void* const* d_in, const int* in_sizes, int n_in,
                              void* d_out, int out_size, void* d_ws, size_t ws_size,
                              hipStream_t stream) {
  const float* x = (const float*)d_in[0];   // [8192][256]
  const float* H = (const float*)d_in[1];   // [8192][4096]
  const float* W = (const float*)d_in[2];   // [256][256]
  const float* b = (const float*)d_in[3];   // [256]
  float* out = (float*)d_out;               // [8192][256] f32

  char* ws = (char*)d_ws;
  u16*  HbT  = (u16*)(ws);                                   // 64 MiB  [E][N]
  u16*  xsT  = (u16*)(ws + 67108864ull);                     //  4 MiB  [C][N]
  u16*  tT   = (u16*)(ws + 67108864ull + 4194304ull);        //  2 MiB  [C][E]
  u16*  omid = (u16*)(ws + 67108864ull + 6291456ull);        //  4 MiB  [N][C]
  u16*  Wb   = (u16*)(ws + 67108864ull + 10485760ull);       // 128 KiB [O][C]
  float* dv  = (float*)(ws + 67108864ull + 10616832ull);     // 32 KiB
  float* de  = (float*)(ws + 67108864ull + 10649600ull);     // 16 KiB

  hipMemsetAsync(dv, 0, (NNODE + NEDGE) * sizeof(float), stream);

  prep_h<<<dim3(NNODE / 64, NEDGE / 64), 256, 0, stream>>>(H, HbT, dv, de);
  prep_x<<<dim3(NNODE / 32, NCH / 64), 256, 0, stream>>>(x, dv, xsT);
  prep_w<<<32, 256, 0, stream>>>(W, Wb);

  // GEMM1: t^T = de_inv * (H^T @ xs)  -> tT [C][E]
  gemm_nt<64, 64, 1><<<dim3(NEDGE / 64, NCH / 64), 256, 0, stream>>>(
      HbT, xsT, NEDGE, NCH, NNODE, de, tT);
  // GEMM2: omid = dv_is * (H @ t)     -> omid [N][C] bf16 (A staged from f32 H)
  gemm_nt<128, 64, 2><<<dim3(NNODE / 128, NCH / 64), 256, 0, stream>>>(
      H, tT, NNODE, NCH, NEDGE, dv, omid);
  // GEMM3: out = omid @ W^T + b       -> d_out f32
  gemm_nt<64, 64, 3><<<dim3(NNODE / 64, NCH / 64), 256, 0, stream>>>(
      omid, Wb, NNODE, NCH, NCH, b, out);
}

// Round 2
// 417.689 us; speedup vs baseline: 1.4354x; 1.4354x over previous
//
#include <hip/hip_runtime.h>

#define NNODE 8192
#define NEDGE 4096
#define NCH   256
#define EPSV  1e-6f

typedef float  f32x4  __attribute__((ext_vector_type(4)));
typedef short  bf16x8 __attribute__((ext_vector_type(8)));
typedef unsigned short u16;
typedef unsigned int   u32;

static __device__ __forceinline__ u16 f2bf(float f) {
  union { float f; u32 u; } c; c.f = f;
  return (u16)((c.u + 0x7FFFu + ((c.u >> 16) & 1u)) >> 16);  // RNE
}

// ---------------------------------------------------------------------------
// prep_h: one pass over H (f32, [NNODE][NEDGE]):
//   d_v/d_e degree sums (LDS partials -> global atomics) + HbT[e][n] bf16.
// grid (NNODE/64, NEDGE/64), 256 threads
// ---------------------------------------------------------------------------
__global__ __launch_bounds__(256) void prep_h(const float* __restrict__ H,
                                              u16* __restrict__ HbT,
                                              float* __restrict__ d_v,
                                              float* __restrict__ d_e) {
  __shared__ u16  Tb[64][65];
  __shared__ float rs[64], cs[64];
  const int tid = threadIdx.x;
  const int r0 = blockIdx.x * 64;
  const int c0 = blockIdx.y * 64;
  if (tid < 64) { rs[tid] = 0.f; cs[tid] = 0.f; }
  __syncthreads();

  const int rowb = tid >> 4;
  const int c4   = tid & 15;
  float colacc[4] = {0.f, 0.f, 0.f, 0.f};
  #pragma unroll
  for (int it = 0; it < 4; ++it) {
    const int row = rowb + it * 16;
    const float4 v = *(const float4*)&H[(size_t)(r0 + row) * NEDGE + c0 + c4 * 4];
    atomicAdd(&rs[row], v.x + v.y + v.z + v.w);
    colacc[0] += v.x; colacc[1] += v.y; colacc[2] += v.z; colacc[3] += v.w;
    Tb[row][c4 * 4 + 0] = f2bf(v.x);
    Tb[row][c4 * 4 + 1] = f2bf(v.y);
    Tb[row][c4 * 4 + 2] = f2bf(v.z);
    Tb[row][c4 * 4 + 3] = f2bf(v.w);
  }
  #pragma unroll
  for (int j = 0; j < 4; ++j) atomicAdd(&cs[c4 * 4 + j], colacc[j]);
  __syncthreads();

  for (int idx = tid; idx < 512; idx += 256) {
    const int c = idx >> 3, ch = idx & 7;
    u16 pk[8];
    #pragma unroll
    for (int e = 0; e < 8; ++e) pk[e] = Tb[ch * 8 + e][c];
    uint4 v;
    v.x = (u32)pk[0] | ((u32)pk[1] << 16);
    v.y = (u32)pk[2] | ((u32)pk[3] << 16);
    v.z = (u32)pk[4] | ((u32)pk[5] << 16);
    v.w = (u32)pk[6] | ((u32)pk[7] << 16);
    *(uint4*)&HbT[(size_t)(c0 + c) * NNODE + r0 + ch * 8] = v;
  }
  if (tid < 64)       atomicAdd(&d_e[c0 + tid], cs[tid]);
  else if (tid < 128) atomicAdd(&d_v[r0 + tid - 64], rs[tid - 64]);
}

// ---------------------------------------------------------------------------
// prep_x: xsT[c][n] = bf16( x[n][c] * rsqrt(d_v[n]+eps) ), [NCH][NNODE]
// ---------------------------------------------------------------------------
__global__ __launch_bounds__(256) void prep_x(const float* __restrict__ x,
                                              const float* __restrict__ d_v,
                                              u16* __restrict__ xsT) {
  const int tid = threadIdx.x;
  const int c  = blockIdx.y * 64 + (tid & 63);
  const int n0 = blockIdx.x * 32 + (tid >> 6) * 8;
  u16 pk[8];
  #pragma unroll
  for (int i = 0; i < 8; ++i) {
    const int n = n0 + i;
    const float s = rsqrtf(d_v[n] + EPSV);
    pk[i] = f2bf(x[(size_t)n * NCH + c] * s);
  }
  uint4 v;
  v.x = (u32)pk[0] | ((u32)pk[1] << 16);
  v.y = (u32)pk[2] | ((u32)pk[3] << 16);
  v.z = (u32)pk[4] | ((u32)pk[5] << 16);
  v.w = (u32)pk[6] | ((u32)pk[7] << 16);
  *(uint4*)&xsT[(size_t)c * NNODE + n0] = v;
}

__global__ __launch_bounds__(256) void prep_w(const float* __restrict__ W,
                                              u16* __restrict__ Wb) {
  const int i = (blockIdx.x * 256 + threadIdx.x) * 8;
  const float4 a = *(const float4*)&W[i];
  const float4 b = *(const float4*)&W[i + 4];
  uint4 v;
  v.x = (u32)f2bf(a.x) | ((u32)f2bf(a.y) << 16);
  v.y = (u32)f2bf(a.z) | ((u32)f2bf(a.w) << 16);
  v.z = (u32)f2bf(b.x) | ((u32)f2bf(b.y) << 16);
  v.w = (u32)f2bf(b.z) | ((u32)f2bf(b.w) << 16);
  *(uint4*)&Wb[i] = v;
}

// init_out: out[n][o] = b[o]  (bias pre-init; GEMM2' atomically accumulates)
__global__ __launch_bounds__(256) void init_out(const float* __restrict__ b,
                                                float* __restrict__ out) {
  const int i = (blockIdx.x * 256 + threadIdx.x) * 4;
  const float4 bb = *(const float4*)&b[i & 255];
  *(float4*)&out[i] = bb;
}

// reduce1: t[e][c] = bf16( tAcc[e][c] / (d_e[e]+eps) )
__global__ __launch_bounds__(256) void reduce1(const float* __restrict__ tAcc,
                                               const float* __restrict__ de,
                                               u16* __restrict__ t) {
  const int base = (blockIdx.x * 256 + threadIdx.x) * 8;
  const int e = base >> 8;
  const float inv = 1.0f / (de[e] + EPSV);
  const float4 a = *(const float4*)&tAcc[base];
  const float4 b = *(const float4*)&tAcc[base + 4];
  uint4 v;
  v.x = (u32)f2bf(a.x * inv) | ((u32)f2bf(a.y * inv) << 16);
  v.y = (u32)f2bf(a.z * inv) | ((u32)f2bf(a.w * inv) << 16);
  v.z = (u32)f2bf(b.x * inv) | ((u32)f2bf(b.y * inv) << 16);
  v.w = (u32)f2bf(b.z * inv) | ((u32)f2bf(b.w * inv) << 16);
  *(uint4*)&t[base] = v;
}

// ---------------------------------------------------------------------------
// NT GEMM with split-K: C[m][n] = sum_k A[m][k] * Bt[n][k]
// WM x WN waves; per-wave tile (BM/WM) x (BN/WN); BK=64; swizzled LDS.
// ASRC: 0 = A bf16; 1 = A f32 (converted + row-scaled during staging)
// SCALE (ASRC=1): 2 = rsqrt(sv[row]+eps)
// EPI: 0 = atomicAdd f32 into Cout (ldc stride)
//      1 = bf16 transposed store: CT[col*M + row] (uint2, 4 rows)
// ---------------------------------------------------------------------------
template <int BM, int BN, int WM, int WN, int ASRC, int SCALE, int EPI>
__global__ __launch_bounds__(WM * WN * 64) void gemm_nt(
    const void* __restrict__ Aptr, const u16* __restrict__ Bt,
    int M, int K, int KC,
    const float* __restrict__ sv,
    void* __restrict__ Cout, int ldc) {
  constexpr int BK = 64;
  constexpr int NT = WM * WN * 64;
  constexpr int WMR = BM / WM, WNR = BN / WN;
  constexpr int FM = WMR / 16, FN = WNR / 16;
  __shared__ u16 lds_a[BM * BK];
  __shared__ u16 lds_b[BN * BK];

  const int tid  = threadIdx.x;
  const int lane = tid & 63;
  const int w    = tid >> 6;
  const int wm   = w / WN, wn = w % WN;
  const int m0   = blockIdx.x * BM;
  const int n0   = blockIdx.y * BN;
  const int k0   = blockIdx.z * KC;

  f32x4 acc[FM][FN];
  #pragma unroll
  for (int fm = 0; fm < FM; ++fm)
    #pragma unroll
    for (int fn = 0; fn < FN; ++fn)
      acc[fm][fn] = (f32x4){0.f, 0.f, 0.f, 0.f};

  for (int kt = k0; kt < k0 + KC; kt += BK) {
    __syncthreads();
    // ---- stage A [BM][BK] ----
    if constexpr (ASRC == 1) {
      const float* A = (const float*)Aptr;
      for (int idx = tid; idx < BM * 8; idx += NT) {
        const int row = idx >> 3, ch = idx & 7;
        float s = 1.0f;
        if constexpr (SCALE == 2) s = rsqrtf(sv[m0 + row] + EPSV);
        const size_t g = (size_t)(m0 + row) * K + kt + ch * 8;
        const float4 v0 = *(const float4*)&A[g];
        const float4 v1 = *(const float4*)&A[g + 4];
        uint4 pv;
        pv.x = (u32)f2bf(v0.x * s) | ((u32)f2bf(v0.y * s) << 16);
        pv.y = (u32)f2bf(v0.z * s) | ((u32)f2bf(v0.w * s) << 16);
        pv.z = (u32)f2bf(v1.x * s) | ((u32)f2bf(v1.y * s) << 16);
        pv.w = (u32)f2bf(v1.z * s) | ((u32)f2bf(v1.w * s) << 16);
        *(uint4*)&lds_a[row * BK + ((ch ^ (row & 7)) * 8)] = pv;
      }
    } else {
      const u16* A = (const u16*)Aptr;
      for (int idx = tid; idx < BM * 8; idx += NT) {
        const int row = idx >> 3, ch = idx & 7;
        *(uint4*)&lds_a[row * BK + ((ch ^ (row & 7)) * 8)] =
            *(const uint4*)&A[(size_t)(m0 + row) * K + kt + ch * 8];
      }
    }
    // ---- stage B [BN][BK] ----
    for (int idx = tid; idx < BN * 8; idx += NT) {
      const int row = idx >> 3, ch = idx & 7;
      *(uint4*)&lds_b[row * BK + ((ch ^ (row & 7)) * 8)] =
          *(const uint4*)&Bt[(size_t)(n0 + row) * K + kt + ch * 8];
    }
    __syncthreads();

    #pragma unroll
    for (int kk = 0; kk < 2; ++kk) {
      bf16x8 af[FM], bfv[FN];
      #pragma unroll
      for (int fm = 0; fm < FM; ++fm) {
        const int row = wm * WMR + fm * 16 + (lane & 15);
        const int ch  = kk * 4 + (lane >> 4);
        af[fm] = *(const bf16x8*)&lds_a[row * BK + ((ch ^ (row & 7)) * 8)];
      }
      #pragma unroll
      for (int fn = 0; fn < FN; ++fn) {
        const int row = wn * WNR + fn * 16 + (lane & 15);
        const int ch  = kk * 4 + (lane >> 4);
        bfv[fn] = *(const bf16x8*)&lds_b[row * BK + ((ch ^ (row & 7)) * 8)];
      }
      #pragma unroll
      for (int fm = 0; fm < FM; ++fm)
        #pragma unroll
        for (int fn = 0; fn < FN; ++fn)
          acc[fm][fn] = __builtin_amdgcn_mfma_f32_16x16x32_bf16(
              af[fm], bfv[fn], acc[fm][fn], 0, 0, 0);
    }
  }

  // ---- epilogue ----
  if constexpr (EPI == 0) {
    float* C = (float*)Cout;
    #pragma unroll
    for (int fm = 0; fm < FM; ++fm) {
      const int rowb = m0 + wm * WMR + fm * 16 + ((lane >> 4) << 2);
      #pragma unroll
      for (int fn = 0; fn < FN; ++fn) {
        const int col = n0 + wn * WNR + fn * 16 + (lane & 15);
        #pragma unroll
        for (int r = 0; r < 4; ++r)
          atomicAdd(&C[(size_t)(rowb + r) * ldc + col], acc[fm][fn][r]);
      }
    }
  } else {
    u16* CT = (u16*)Cout;
    #pragma unroll
    for (int fm = 0; fm < FM; ++fm) {
      const int rowb = m0 + wm * WMR + fm * 16 + ((lane >> 4) << 2);
      #pragma unroll
      for (int fn = 0; fn < FN; ++fn) {
        const int col = n0 + wn * WNR + fn * 16 + (lane & 15);
        uint2 v;
        v.x = (u32)f2bf(acc[fm][fn][0]) | ((u32)f2bf(acc[fm][fn][1]) << 16);
        v.y = (u32)f2bf(acc[fm][fn][2]) | ((u32)f2bf(acc[fm][fn][3]) << 16);
        *(uint2*)&CT[(size_t)col * M + rowb] = v;
      }
    }
  }
}

// ---------------------------------------------------------------------------
extern "C" void kernel_launch(void* const* d_in, const int* in_sizes, int n_in,
                              void* d_out, int out_size, void* d_ws, size_t ws_size,
                              hipStream_t stream) {
  const float* x = (const float*)d_in[0];   // [8192][256]
  const float* H = (const float*)d_in[1];   // [8192][4096]
  const float* W = (const float*)d_in[2];   // [256][256]
  const float* b = (const float*)d_in[3];   // [256]
  float* out = (float*)d_out;               // [8192][256] f32

  char* ws = (char*)d_ws;
  u16*   HbT  = (u16*)(ws);                          // 64 MiB  [E][N] bf16
  u16*   xsT  = (u16*)(ws + 67108864ull);            //  4 MiB  [C][N] bf16
  float* tAcc = (float*)(ws + 71303168ull);          //  4 MiB  [E][C] f32
  u16*   t    = (u16*)(ws + 75497472ull);            //  2 MiB  [E][C] bf16
  u16*   uT   = (u16*)(ws + 77594624ull);            //  2 MiB  [O][E] bf16
  u16*   Wb   = (u16*)(ws + 79691776ull);            // 128 KiB [O][C] bf16
  float* dv   = (float*)(ws + 79822848ull);          // 32 KiB
  float* de   = (float*)(ws + 79855616ull);          // 16 KiB

  hipMemsetAsync(dv, 0, (NNODE + NEDGE) * sizeof(float), stream);
  hipMemsetAsync(tAcc, 0, (size_t)NEDGE * NCH * sizeof(float), stream);

  prep_h<<<dim3(NNODE / 64, NEDGE / 64), 256, 0, stream>>>(H, HbT, dv, de);
  prep_x<<<dim3(NNODE / 32, NCH / 64), 256, 0, stream>>>(x, dv, xsT);
  prep_w<<<32, 256, 0, stream>>>(W, Wb);
  init_out<<<(NNODE * NCH) / 1024, 256, 0, stream>>>(b, out);

  // GEMM1: tAcc[e][c] += sum_n HbT[e][n]*xsT[c][n]   (split-K S=8)
  gemm_nt<64, 256, 2, 4, 0, 0, 0><<<dim3(NEDGE / 64, 1, 8), 512, 0, stream>>>(
      HbT, xsT, NEDGE, NNODE, NNODE / 8, nullptr, tAcc, NCH);
  // t = bf16(de_inv * tAcc)
  reduce1<<<(NEDGE * NCH) / 2048, 256, 0, stream>>>(tAcc, de, t);
  // GEMM-W: uT[o][e] = sum_c t[e][c]*Wb[o][c]   (transposed bf16 store)
  gemm_nt<64, 64, 2, 2, 0, 0, 1><<<dim3(NEDGE / 64, NCH / 64, 1), 256, 0, stream>>>(
      t, Wb, NEDGE, NCH, NCH, nullptr, uT, 0);
  // GEMM2': out[n][o] += sum_e (dv_is[n]*H[n][e]) * uT[o][e]  (split-K S=4,
  // bias pre-initialized by init_out)
  gemm_nt<64, 256, 2, 4, 1, 2, 0><<<dim3(NNODE / 64, 1, 4), 512, 0, stream>>>(
      H, uT, NNODE, NEDGE, NEDGE / 4, dv, out, NCH);
}

// Round 3
// 353.157 us; speedup vs baseline: 1.6977x; 1.1827x over previous
//
#include <hip/hip_runtime.h>

#define NNODE 8192
#define NEDGE 4096
#define NCH   256
#define EPSV  1e-6f

typedef float  f32x4  __attribute__((ext_vector_type(4)));
typedef short  bf16x8 __attribute__((ext_vector_type(8)));
typedef unsigned short u16;
typedef unsigned int   u32;

static __device__ __forceinline__ u16 f2bf(float f) {
  union { float f; u32 u; } c; c.f = f;
  return (u16)((c.u + 0x7FFFu + ((c.u >> 16) & 1u)) >> 16);  // RNE
}

// async global->LDS, 16 B per lane; LDS dest is wave-uniform base + lane*16
static __device__ __forceinline__ void gload16(const u16* g, u16* l) {
  __builtin_amdgcn_global_load_lds((const __attribute__((address_space(1))) void*)g,
                                   (__attribute__((address_space(3))) void*)l,
                                   16, 0, 0);
}

// ---------------------------------------------------------------------------
// prep_h: one pass over H f32 [NNODE][NEDGE]:
//   Hb[n][e] bf16, HbT[e][n] bf16 (LDS transpose), d_v row sums, d_e col sums.
//   NO LDS atomics: shuffle-reduced rows, partial-array columns.
// grid (NNODE/64, NEDGE/64), 256 threads
// ---------------------------------------------------------------------------
__global__ __launch_bounds__(256) void prep_h(const float* __restrict__ H,
                                              u16* __restrict__ Hb,
                                              u16* __restrict__ HbT,
                                              float* __restrict__ d_v,
                                              float* __restrict__ d_e) {
  __shared__ u16  Tb[64][65];
  __shared__ float csp[16][65];
  __shared__ float rsum[64];
  const int tid = threadIdx.x;
  const int r0 = blockIdx.x * 64;
  const int c0 = blockIdx.y * 64;
  const int rowb = tid >> 4;        // 0..15
  const int c4   = tid & 15;        // 0..15

  float colacc[4] = {0.f, 0.f, 0.f, 0.f};
  #pragma unroll
  for (int it = 0; it < 4; ++it) {
    const int row = rowb + it * 16;
    const float4 v = *(const float4*)&H[(size_t)(r0 + row) * NEDGE + c0 + c4 * 4];
    float rp = v.x + v.y + v.z + v.w;
    rp += __shfl_xor(rp, 1); rp += __shfl_xor(rp, 2);
    rp += __shfl_xor(rp, 4); rp += __shfl_xor(rp, 8);
    if (c4 == 0) rsum[row] = rp;
    colacc[0] += v.x; colacc[1] += v.y; colacc[2] += v.z; colacc[3] += v.w;
    const u16 b0 = f2bf(v.x), b1 = f2bf(v.y), b2 = f2bf(v.z), b3 = f2bf(v.w);
    Tb[row][c4 * 4 + 0] = b0; Tb[row][c4 * 4 + 1] = b1;
    Tb[row][c4 * 4 + 2] = b2; Tb[row][c4 * 4 + 3] = b3;
    uint2 hv;
    hv.x = (u32)b0 | ((u32)b1 << 16);
    hv.y = (u32)b2 | ((u32)b3 << 16);
    *(uint2*)&Hb[(size_t)(r0 + row) * NEDGE + c0 + c4 * 4] = hv;
  }
  #pragma unroll
  for (int j = 0; j < 4; ++j) csp[rowb][c4 * 4 + j] = colacc[j];
  __syncthreads();

  // transposed write: HbT[c0+c][r0 + ch*8 .. +7]
  for (int idx = tid; idx < 512; idx += 256) {
    const int c = idx >> 3, ch = idx & 7;
    u16 pk[8];
    #pragma unroll
    for (int e = 0; e < 8; ++e) pk[e] = Tb[ch * 8 + e][c];
    uint4 v;
    v.x = (u32)pk[0] | ((u32)pk[1] << 16);
    v.y = (u32)pk[2] | ((u32)pk[3] << 16);
    v.z = (u32)pk[4] | ((u32)pk[5] << 16);
    v.w = (u32)pk[6] | ((u32)pk[7] << 16);
    *(uint4*)&HbT[(size_t)(c0 + c) * NNODE + r0 + ch * 8] = v;
  }
  if (tid < 64) {
    float s = 0.f;
    #pragma unroll
    for (int r = 0; r < 16; ++r) s += csp[r][tid];
    atomicAdd(&d_e[c0 + tid], s);
    atomicAdd(&d_v[r0 + tid], rsum[tid]);
  }
}

// ---------------------------------------------------------------------------
// prep_x: xsT[c][n] = bf16( x[n][c] * rsqrt(d_v[n]+eps) ), [NCH][NNODE]
// ---------------------------------------------------------------------------
__global__ __launch_bounds__(256) void prep_x(const float* __restrict__ x,
                                              const float* __restrict__ d_v,
                                              u16* __restrict__ xsT) {
  const int tid = threadIdx.x;
  const int c  = blockIdx.y * 64 + (tid & 63);
  const int n0 = blockIdx.x * 32 + (tid >> 6) * 8;
  u16 pk[8];
  #pragma unroll
  for (int i = 0; i < 8; ++i) {
    const int n = n0 + i;
    const float s = rsqrtf(d_v[n] + EPSV);
    pk[i] = f2bf(x[(size_t)n * NCH + c] * s);
  }
  uint4 v;
  v.x = (u32)pk[0] | ((u32)pk[1] << 16);
  v.y = (u32)pk[2] | ((u32)pk[3] << 16);
  v.z = (u32)pk[4] | ((u32)pk[5] << 16);
  v.w = (u32)pk[6] | ((u32)pk[7] << 16);
  *(uint4*)&xsT[(size_t)c * NNODE + n0] = v;
}

__global__ __launch_bounds__(256) void prep_w(const float* __restrict__ W,
                                              u16* __restrict__ Wb) {
  const int i = (blockIdx.x * 256 + threadIdx.x) * 8;
  const float4 a = *(const float4*)&W[i];
  const float4 b = *(const float4*)&W[i + 4];
  uint4 v;
  v.x = (u32)f2bf(a.x) | ((u32)f2bf(a.y) << 16);
  v.y = (u32)f2bf(a.z) | ((u32)f2bf(a.w) << 16);
  v.z = (u32)f2bf(b.x) | ((u32)f2bf(b.y) << 16);
  v.w = (u32)f2bf(b.z) | ((u32)f2bf(b.w) << 16);
  *(uint4*)&Wb[i] = v;
}

// init_out: out[n][o] = b[o]
__global__ __launch_bounds__(256) void init_out(const float* __restrict__ b,
                                                float* __restrict__ out) {
  const int i = (blockIdx.x * 256 + threadIdx.x) * 4;
  const float4 bb = *(const float4*)&b[i & 255];
  *(float4*)&out[i] = bb;
}

// ---------------------------------------------------------------------------
// NT GEMM, split-K: C[m][n] = sum_k A[m][k] * Bt[n][k], bf16 MFMA 16x16x32.
// B always bf16 staged via global_load_lds (pre-swizzled source, linear LDS).
// ASRC: 0 = A bf16 gload_lds; 1 = A f32 reg-staged, scaled by 1/(sva[row]+eps)
// EPI : 0 = atomicAdd f32 (ldc); 1 = atomicAdd f32 * rsqrt(sve[row]+eps);
//       2 = transposed bf16 store CT[col*M+row] (uint2)
// ---------------------------------------------------------------------------
template <int ROWS, int NT>
static __device__ __forceinline__ void stage_gl(const u16* __restrict__ base,
                                                int row0, int K, int kt,
                                                u16* lds, int tid) {
  const int w = tid >> 6, l = tid & 63;
  #pragma unroll
  for (int i = 0; i < (ROWS * 8) / NT; ++i) {
    const int slot = i * NT + w * 64 + l;
    const int row = slot >> 3, ch = slot & 7;
    const int sch = ch ^ (row & 7);                 // pre-swizzled source
    gload16(base + (size_t)(row0 + row) * K + kt + sch * 8,
            lds + (size_t)(i * NT + w * 64) * 8);   // wave-uniform LDS base
  }
}

template <int BM, int BN, int WM, int WN, int ASRC, int EPI>
__global__ __launch_bounds__(WM * WN * 64) void gemm_nt(
    const void* __restrict__ Aptr, const u16* __restrict__ Bt,
    int M, int K, int KC,
    const float* __restrict__ sva, const float* __restrict__ sve,
    void* __restrict__ Cout, int ldc) {
  constexpr int BK = 64;
  constexpr int NT = WM * WN * 64;
  constexpr int WMR = BM / WM, WNR = BN / WN;
  constexpr int FM = WMR / 16, FN = WNR / 16;
  __shared__ u16 lds_a[BM * BK];
  __shared__ u16 lds_b[BN * BK];

  const int tid  = threadIdx.x;
  const int lane = tid & 63;
  const int w    = tid >> 6;
  const int wm   = w / WN, wn = w % WN;
  const int m0   = blockIdx.x * BM;
  const int n0   = blockIdx.y * BN;
  const int k0   = blockIdx.z * KC;

  f32x4 acc[FM][FN];
  #pragma unroll
  for (int fm = 0; fm < FM; ++fm)
    #pragma unroll
    for (int fn = 0; fn < FN; ++fn)
      acc[fm][fn] = (f32x4){0.f, 0.f, 0.f, 0.f};

  for (int kt = k0; kt < k0 + KC; kt += BK) {
    __syncthreads();
    if constexpr (ASRC == 0) {
      stage_gl<BM, NT>((const u16*)Aptr, m0, K, kt, lds_a, tid);
    } else {
      const float* A = (const float*)Aptr;
      for (int idx = tid; idx < BM * 8; idx += NT) {
        const int row = idx >> 3, ch = idx & 7;
        const float s = 1.0f / (sva[m0 + row] + EPSV);
        const size_t g = (size_t)(m0 + row) * K + kt + ch * 8;
        const float4 v0 = *(const float4*)&A[g];
        const float4 v1 = *(const float4*)&A[g + 4];
        uint4 pv;
        pv.x = (u32)f2bf(v0.x * s) | ((u32)f2bf(v0.y * s) << 16);
        pv.y = (u32)f2bf(v0.z * s) | ((u32)f2bf(v0.w * s) << 16);
        pv.z = (u32)f2bf(v1.x * s) | ((u32)f2bf(v1.y * s) << 16);
        pv.w = (u32)f2bf(v1.z * s) | ((u32)f2bf(v1.w * s) << 16);
        *(uint4*)&lds_a[row * BK + ((ch ^ (row & 7)) * 8)] = pv;
      }
    }
    stage_gl<BN, NT>(Bt, n0, K, kt, lds_b, tid);
    __syncthreads();

    #pragma unroll
    for (int kk = 0; kk < 2; ++kk) {
      bf16x8 af[FM], bfv[FN];
      #pragma unroll
      for (int fm = 0; fm < FM; ++fm) {
        const int row = wm * WMR + fm * 16 + (lane & 15);
        const int ch  = kk * 4 + (lane >> 4);
        af[fm] = *(const bf16x8*)&lds_a[row * BK + ((ch ^ (row & 7)) * 8)];
      }
      #pragma unroll
      for (int fn = 0; fn < FN; ++fn) {
        const int row = wn * WNR + fn * 16 + (lane & 15);
        const int ch  = kk * 4 + (lane >> 4);
        bfv[fn] = *(const bf16x8*)&lds_b[row * BK + ((ch ^ (row & 7)) * 8)];
      }
      #pragma unroll
      for (int fm = 0; fm < FM; ++fm)
        #pragma unroll
        for (int fn = 0; fn < FN; ++fn)
          acc[fm][fn] = __builtin_amdgcn_mfma_f32_16x16x32_bf16(
              af[fm], bfv[fn], acc[fm][fn], 0, 0, 0);
    }
  }

  if constexpr (EPI == 0) {
    float* C = (float*)Cout;
    #pragma unroll
    for (int fm = 0; fm < FM; ++fm) {
      const int rowb = m0 + wm * WMR + fm * 16 + ((lane >> 4) << 2);
      #pragma unroll
      for (int fn = 0; fn < FN; ++fn) {
        const int col = n0 + wn * WNR + fn * 16 + (lane & 15);
        #pragma unroll
        for (int r = 0; r < 4; ++r)
          atomicAdd(&C[(size_t)(rowb + r) * ldc + col], acc[fm][fn][r]);
      }
    }
  } else if constexpr (EPI == 1) {
    float* C = (float*)Cout;
    #pragma unroll
    for (int fm = 0; fm < FM; ++fm) {
      const int rowb = m0 + wm * WMR + fm * 16 + ((lane >> 4) << 2);
      float s[4];
      #pragma unroll
      for (int r = 0; r < 4; ++r) s[r] = rsqrtf(sve[rowb + r] + EPSV);
      #pragma unroll
      for (int fn = 0; fn < FN; ++fn) {
        const int col = n0 + wn * WNR + fn * 16 + (lane & 15);
        #pragma unroll
        for (int r = 0; r < 4; ++r)
          atomicAdd(&C[(size_t)(rowb + r) * ldc + col], acc[fm][fn][r] * s[r]);
      }
    }
  } else {
    u16* CT = (u16*)Cout;
    #pragma unroll
    for (int fm = 0; fm < FM; ++fm) {
      const int rowb = m0 + wm * WMR + fm * 16 + ((lane >> 4) << 2);
      #pragma unroll
      for (int fn = 0; fn < FN; ++fn) {
        const int col = n0 + wn * WNR + fn * 16 + (lane & 15);
        uint2 v;
        v.x = (u32)f2bf(acc[fm][fn][0]) | ((u32)f2bf(acc[fm][fn][1]) << 16);
        v.y = (u32)f2bf(acc[fm][fn][2]) | ((u32)f2bf(acc[fm][fn][3]) << 16);
        *(uint2*)&CT[(size_t)col * M + rowb] = v;
      }
    }
  }
}

// ---------------------------------------------------------------------------
extern "C" void kernel_launch(void* const* d_in, const int* in_sizes, int n_in,
                              void* d_out, int out_size, void* d_ws, size_t ws_size,
                              hipStream_t stream) {
  const float* x = (const float*)d_in[0];   // [8192][256]
  const float* H = (const float*)d_in[1];   // [8192][4096]
  const float* W = (const float*)d_in[2];   // [256][256]
  const float* b = (const float*)d_in[3];   // [256]
  float* out = (float*)d_out;               // [8192][256] f32

  char* ws = (char*)d_ws;
  u16*   HbT  = (u16*)(ws);                          // 64 MiB  [E][N] bf16
  u16*   Hb   = (u16*)(ws + 67108864ull);            // 64 MiB  [N][E] bf16
  u16*   xsT  = (u16*)(ws + 134217728ull);           //  4 MiB  [C][N] bf16
  float* tAcc = (float*)(ws + 138412032ull);         //  4 MiB  [E][C] f32
  u16*   uT   = (u16*)(ws + 142606336ull);           //  2 MiB  [O][E] bf16
  u16*   Wb   = (u16*)(ws + 144703488ull);           // 128 KiB [O][C] bf16
  float* dv   = (float*)(ws + 144834560ull);         // 32 KiB
  float* de   = (float*)(ws + 144867328ull);         // 16 KiB

  hipMemsetAsync(dv, 0, (NNODE + NEDGE) * sizeof(float), stream);
  hipMemsetAsync(tAcc, 0, (size_t)NEDGE * NCH * sizeof(float), stream);

  prep_h<<<dim3(NNODE / 64, NEDGE / 64), 256, 0, stream>>>(H, Hb, HbT, dv, de);
  prep_x<<<dim3(NNODE / 32, NCH / 64), 256, 0, stream>>>(x, dv, xsT);
  prep_w<<<32, 256, 0, stream>>>(W, Wb);
  init_out<<<(NNODE * NCH) / 1024, 256, 0, stream>>>(b, out);

  // GEMM1: tAcc[e][c] += sum_n HbT[e][n]*xsT[c][n]   (split-K S=8)
  gemm_nt<64, 256, 1, 4, 0, 0><<<dim3(NEDGE / 64, 1, 8), 256, 0, stream>>>(
      HbT, xsT, NEDGE, NNODE, NNODE / 8, nullptr, nullptr, tAcc, NCH);
  // GEMM-W: uT[o][e] = sum_c (de_inv[e]*tAcc[e][c]) * Wb[o][c]
  //         computed as C[e][o], transposed bf16 store -> uT [O][E]
  gemm_nt<64, 256, 1, 4, 1, 2><<<dim3(NEDGE / 64, 1, 1), 256, 0, stream>>>(
      tAcc, Wb, NEDGE, NCH, NCH, de, nullptr, uT, 0);
  // GEMM2': out[n][o] += rsqrt(dv[n]) * sum_e Hb[n][e]*uT[o][e]  (split-K S=4)
  gemm_nt<64, 256, 1, 4, 0, 1><<<dim3(NNODE / 64, 1, 4), 256, 0, stream>>>(
      Hb, uT, NNODE, NEDGE, NEDGE / 4, nullptr, dv, out, NCH);
}